// Round 14
// baseline (251.320 us; speedup 1.0000x reference)
//
#include <hip/hip_runtime.h>

// Problem constants (from reference)
#define NB     32      // B
#define NPTS   2048    // N
#define KNN    16      // K
#define FIN    32      // F_IN
#define FOUT   64      // F_OUT

typedef __attribute__((ext_vector_type(8))) short bf16x8;
typedef __attribute__((ext_vector_type(4))) float f32x4;

// RNE float->bf16 pack
__device__ inline unsigned bf16pk(float lo, float hi) {
    unsigned a = __float_as_uint(lo), b = __float_as_uint(hi);
    a = (a + 0x7fffu + ((a >> 16) & 1u)) >> 16;
    b = (b + 0x7fffu + ((b >> 16) & 1u)) >> 16;
    return (a & 0xffffu) | (b << 16);
}

// ---------------------------------------------------------------------------
// R14: R13 + (1) depth-1 software pipeline in select AND rescan — extract d2
// from the current 16 staged candidates, then issue the next batch's loads,
// then sort/APP while they fly (sort 440-568 cyc > ~200 cyc L2 latency).
// exw wave's 3-range split replaced by one unified loop with the j==q
// compare always-on FOR THAT WAVE ONLY (identical semantics; j==q true at
// most once). Candidate order / merge order / tie machinery unchanged ->
// bit-identical kNN. (2) parallel gather: all 8 waves place their own
// chunk's JL entries via CNTS prefix sums (disjoint positions; strict-then-
// ties order provably identical; pos<16 guard on every write for safety).
// ---------------------------------------------------------------------------

#define CEA(x, y) { float _t = fminf(x, y); y = fmaxf(x, y); x = _t; }
#define CED(x, y) { float _t = fmaxf(x, y); y = fminf(x, y); x = _t; }

#define BMERGE16(dk) \
    CEA(dk[0],dk[8])  CEA(dk[1],dk[9])  CEA(dk[2],dk[10]) CEA(dk[3],dk[11]) \
    CEA(dk[4],dk[12]) CEA(dk[5],dk[13]) CEA(dk[6],dk[14]) CEA(dk[7],dk[15]) \
    CEA(dk[0],dk[4])  CEA(dk[1],dk[5])  CEA(dk[2],dk[6])  CEA(dk[3],dk[7])  \
    CEA(dk[8],dk[12]) CEA(dk[9],dk[13]) CEA(dk[10],dk[14]) CEA(dk[11],dk[15]) \
    CEA(dk[0],dk[2])  CEA(dk[1],dk[3])  CEA(dk[4],dk[6])  CEA(dk[5],dk[7])  \
    CEA(dk[8],dk[10]) CEA(dk[9],dk[11]) CEA(dk[12],dk[14]) CEA(dk[13],dk[15]) \
    CEA(dk[0],dk[1])  CEA(dk[2],dk[3])  CEA(dk[4],dk[5])  CEA(dk[6],dk[7])  \
    CEA(dk[8],dk[9])  CEA(dk[10],dk[11]) CEA(dk[12],dk[13]) CEA(dk[14],dk[15])

#define NET8(a) \
    CED(a[0],a[1]) CED(a[2],a[3]) CED(a[4],a[5]) CED(a[6],a[7]) \
    CED(a[0],a[2]) CED(a[1],a[3]) CED(a[4],a[6]) CED(a[5],a[7]) \
    CED(a[1],a[2]) CED(a[5],a[6]) \
    CED(a[0],a[4]) CED(a[1],a[5]) CED(a[2],a[6]) CED(a[3],a[7]) \
    CED(a[2],a[4]) CED(a[3],a[5]) \
    CED(a[1],a[2]) CED(a[3],a[4]) CED(a[5],a[6])

// ================= K1: (x,y,z,sq) precompute (verbatim) ====================
__global__ __launch_bounds__(256) void sq_kernel(
    const float* __restrict__ pos, float4* __restrict__ P4)
{
    const int i = blockIdx.x * 256 + threadIdx.x;   // 0 .. 65535
    const float px = pos[i*3 + 0];
    const float py = pos[i*3 + 1];
    const float pz = pos[i*3 + 2];
    const float sq = __fadd_rn(__fadd_rn(__fmul_rn(px,px), __fmul_rn(py,py)),
                               __fmul_rn(pz,pz));
    P4[i] = make_float4(px, py, pz, sq);
}

// ==================== K2: fused exact 16-NN + edge MLP =====================
#define CH   8
#define CHL  (NPTS / CH)    // 256

// shifted distance: d2' = c.w - 2*dot  (per-query order == true d2 order)
#define D2P(C, DST)                                                        \
    {                                                                      \
        float _dot = __fmaf_rn(me.z, (C).z,                                \
                      __fmaf_rn(me.y, (C).y, __fmul_rn(me.x, (C).x)));     \
        DST = __fmaf_rn(-2.0f, _dot, (C).w);                               \
    }

// rescan append (order within chunk = ascending j -> reference tie-break)
#define APP(DD, JJ)                                                        \
    if ((DD) <= tthr) {                                                    \
        if ((DD) < tthr) {                                                 \
            if (cntS + cntT >= KNN) --cntT;                                \
            JL[base + cntS * 64 + l] = (JJ);                               \
            ++cntS;                                                        \
        } else if (cntS + cntT < KNN) {                                    \
            JL[base + (KNN - 1 - cntT) * 64 + l] = (JJ);                   \
            ++cntT;                                                        \
        }                                                                  \
    }

#define ESTRIDE 66   // padded row stride for E/S
#define IDXS    17   // padded neighbor-list stride (kills gather conflicts)

__global__ __launch_bounds__(512, 8) void knn_mlp_kernel(
    const float4* __restrict__ P4, const float* __restrict__ x,
    const float* __restrict__ W_edge, const float* __restrict__ b_edge,
    const float* __restrict__ W_nn,   const float* __restrict__ b_nn,
    float* __restrict__ out)
{
    // arena: phase A: [V/JL 32768][CNTS 2048][IDX 4352]
    //        phase B: [E 16896][S 16896][... ][IDX 4352]
    __shared__ __attribute__((aligned(16))) char smem[39168];
    float* V    = (float*)smem;
    int*   CNTS = (int*)(smem + 32768);
    int*   IDX  = (int*)(smem + 34816);

    // XCD-aware swizzle: batch b's 32 blocks all share orig%8 == b>>2,
    // i.e. one XCD (dispatch round-robins blockIdx across the 8 XCDs).
    const int orig = blockIdx.x;
    const int b    = ((orig & 7) << 2) | ((orig >> 3) & 3);  // batch 0..31
    const int slab = orig >> 5;                              // slab  0..31
    const int t    = threadIdx.x;
    const int w    = __builtin_amdgcn_readfirstlane(t >> 6);  // chunk id
    const int l    = t & 63;

    const float4* __restrict__ pb4 = P4 + (size_t)b * NPTS;
    const int    q  = slab * 64 + l;     // query within batch (0..2047)
    const float4 me = pb4[q];            // me.w unused (shift dropped)

    const int  j0  = w * CHL;
    const int  exw = slab >> 2;          // chunk containing q's
    const bool ex  = (w == exw);         // wave-uniform

    int* JL = (int*)V;                   // alias used after the merge barrier
    const int base = w * KNN * 64;
    int cntS = 0, cntT = 0;              // live into the parallel gather

    // ======================= Phase A: exact 16-NN ==========================
    {
        float dk[KNN];
        #pragma unroll
        for (int s = 0; s < KNN; ++s) dk[s] = 1e30f;

        // ---- select: unified loop, depth-1 prefetch ----
        {
            float4 cur[16];
            #pragma unroll
            for (int i = 0; i < 16; ++i) cur[i] = pb4[j0 + i];

            for (int jb = j0; jb < j0 + CHL; jb += 16) {
                float a[8], a2[8];
                #pragma unroll
                for (int i = 0; i < 8; ++i) {
                    float d2;
                    D2P(cur[i], d2)
                    a[i] = (ex && (jb + i) == q) ? 1e30f : d2;
                }
                #pragma unroll
                for (int i = 0; i < 8; ++i) {
                    float d2;
                    D2P(cur[8 + i], d2)
                    a2[i] = (ex && (jb + 8 + i) == q) ? 1e30f : d2;
                }
                // issue next batch's loads while sorting (clamped dummy on last)
                const int pjb = (jb + 16 < j0 + CHL) ? (jb + 16) : j0;
                #pragma unroll
                for (int i = 0; i < 16; ++i) cur[i] = pb4[pjb + i];

                NET8(a)
                NET8(a2)
                #pragma unroll
                for (int i = 0; i < 8; ++i) dk[8+i] = fminf(dk[8+i], a[i]);
                BMERGE16(dk)
                #pragma unroll
                for (int i = 0; i < 8; ++i) dk[8+i] = fminf(dk[8+i], a2[i]);
                BMERGE16(dk)
            }
        }

        // cross-chunk merge of the 8 per-chunk top-16 lists
        #pragma unroll
        for (int s = 0; s < KNN; ++s)
            V[(w * KNN + s) * 64 + l] = dk[s];
        __syncthreads();

        for (int c2 = 0; c2 < CH; ++c2) {
            if (c2 == w) continue;
            float v[KNN];
            #pragma unroll
            for (int s2 = 0; s2 < KNN; ++s2)
                v[s2] = V[(c2 * KNN + s2) * 64 + l];
            #pragma unroll
            for (int s = 0; s < KNN; ++s) dk[s] = fminf(dk[s], v[KNN-1-s]);
            BMERGE16(dk)
        }
        const float tthr = dk[KNN-1];
        __syncthreads();            // V dead -> reuse as JL

        // ---- rescan: unified loop, depth-1 prefetch (identical chain) ----
        {
            float4 cur[16];
            #pragma unroll
            for (int i = 0; i < 16; ++i) cur[i] = pb4[j0 + i];

            for (int jb = j0; jb < j0 + CHL; jb += 16) {
                float dd[16];
                #pragma unroll
                for (int i = 0; i < 16; ++i) {
                    float d2;
                    D2P(cur[i], d2)
                    dd[i] = (ex && (jb + i) == q) ? 1e30f : d2;
                }
                const int pjb = (jb + 16 < j0 + CHL) ? (jb + 16) : j0;
                #pragma unroll
                for (int i = 0; i < 16; ++i) cur[i] = pb4[pjb + i];

                #pragma unroll
                for (int i = 0; i < 16; ++i) { APP(dd[i], jb + i) }
            }
        }
        CNTS[w * 64 + l] = cntS | (cntT << 16);
        __syncthreads();
    }

    // ---- parallel gather: all 8 waves, prefix-sum placement ----
    // Wave w places its own chunk's entries. Order identical to the serial
    // gather: strict entries in (chunk, index) order, then ties in (chunk,
    // index) order, capped at 16. Positions disjoint across waves.
    {
        int pS = 0, pT = 0, totS = 0;
        #pragma unroll
        for (int c2 = 0; c2 < CH; ++c2) {
            int cc = CNTS[c2 * 64 + l];
            int cs = cc & 0xffff, ct = cc >> 16;
            if (c2 < w) { pS += cs; pT += ct; }
            totS += cs;
        }
        for (int s2 = 0; s2 < cntS; ++s2) {
            int pos = pS + s2;                    // provably < 16; guard anyway
            if (pos < KNN) IDX[l * IDXS + pos] = JL[base + s2 * 64 + l];
        }
        for (int s2 = 0; s2 < cntT; ++s2) {
            int pos = totS + pT + s2;
            if (pos < KNN)
                IDX[l * IDXS + pos] = JL[base + (KNN - 1 - s2) * 64 + l];
        }
    }
    __syncthreads();            // IDX visible; JL/CNTS dead below

    // ======================= Phase B: MFMA edge MLP ========================
    const int c15 = l & 15;
    const int g   = l >> 4;
    const int nbase = b * NPTS + slab * 64;   // block's first node (global)
    const int gbase = b * NPTS;               // batch start row

    float* E = (float*)smem;            // [64][ESTRIDE]
    float* S = (float*)(smem + 16896);  // [64][ESTRIDE]

    const f32x4 zf = {0.f, 0.f, 0.f, 0.f};

    // ---- B1: base/skip for all 64 nodes -> LDS (wave = 16-node grp x 2 f)
    {
        const int ng = w & 3;            // node group 0..3
        const int f0 = (w >> 2) * 2;     // f-slice base: 0 or 2

        const float* rp = x + (size_t)(nbase + ng * 16 + c15) * FIN + g * 8;
        float4 v0 = *(const float4*)rp;
        float4 v1 = *(const float4*)(rp + 4);
        int4 pk = make_int4(bf16pk(v0.x, v0.y), bf16pk(v0.z, v0.w),
                            bf16pk(v1.x, v1.y), bf16pk(v1.z, v1.w));
        bf16x8 afi = *(bf16x8*)&pk;

        #pragma unroll
        for (int ff = 0; ff < 2; ++ff) {
            const int col = 16 * (f0 + ff) + c15;
            unsigned pd[4], pn[4];
            #pragma unroll
            for (int d = 0; d < 4; ++d) {
                const int k0 = g * 8 + 2 * d;
                float h0 = W_edge[(FIN + k0)     * FOUT + col];
                float h1 = W_edge[(FIN + k0 + 1) * FOUT + col];
                pd[d] = bf16pk(W_edge[k0       * FOUT + col] - h0,
                               W_edge[(k0 + 1) * FOUT + col] - h1);
                pn[d] = bf16pk(W_nn[k0 * FOUT + col], W_nn[(k0+1) * FOUT + col]);
            }
            int4 bd = make_int4(pd[0], pd[1], pd[2], pd[3]);
            int4 bn = make_int4(pn[0], pn[1], pn[2], pn[3]);
            f32x4 baseF = __builtin_amdgcn_mfma_f32_16x16x32_bf16(
                afi, *(bf16x8*)&bd, zf, 0, 0, 0);
            f32x4 skipF = __builtin_amdgcn_mfma_f32_16x16x32_bf16(
                afi, *(bf16x8*)&bn, zf, 0, 0, 0);
            const float be  = b_edge[col];
            const float bnn = b_nn[col];
            #pragma unroll
            for (int reg = 0; reg < 4; ++reg) {
                const int nd = ng * 16 + g * 4 + reg;   // node within block
                E[nd * ESTRIDE + col] = baseF[reg] + be;
                S[nd * ESTRIDE + col] = fmaxf(skipF[reg] + bnn, 0.f);
            }
        }
    }
    __syncthreads();   // E/S visible

    // ---- B2: wave = 8 nodes x ALL 4 f-slices, depth-2 gather prefetch ----
    {
        const int n0l = w * 8;           // first local node of this wave

        int4 Bhi[4];
        #pragma unroll
        for (int ff = 0; ff < 4; ++ff) {
            const int col = 16 * ff + c15;
            unsigned ph[4];
            #pragma unroll
            for (int d = 0; d < 4; ++d) {
                const int k0 = g * 8 + 2 * d;
                ph[d] = bf16pk(W_edge[(FIN + k0)     * FOUT + col],
                               W_edge[(FIN + k0 + 1) * FOUT + col]);
            }
            Bhi[ff] = make_int4(ph[0], ph[1], ph[2], ph[3]);
        }

        // prime depth-2 pipeline (nodes 0 and 1)
        int nbA = IDX[(n0l + 0) * IDXS + c15];
        int nbB = IDX[(n0l + 1) * IDXS + c15];
        const float* rpA = x + (size_t)(gbase + nbA) * FIN + g * 8;
        const float* rpB = x + (size_t)(gbase + nbB) * FIN + g * 8;
        float4 Aa = *(const float4*)rpA, Ab = *(const float4*)(rpA + 4);
        float4 Ba = *(const float4*)rpB, Bb = *(const float4*)(rpB + 4);

        #pragma unroll 1
        for (int i = 0; i < 8; i += 2) {
            // node i (buffer A), prefetch node i+2 into A
            float4 c0 = Aa, c1 = Ab;
            if (i + 2 < 8) {
                int nb = IDX[(n0l + i + 2) * IDXS + c15];
                const float* rp2 = x + (size_t)(gbase + nb) * FIN + g * 8;
                Aa = *(const float4*)rp2;
                Ab = *(const float4*)(rp2 + 4);
            }
            {
                int4 pk2 = make_int4(bf16pk(c0.x, c0.y), bf16pk(c0.z, c0.w),
                                     bf16pk(c1.x, c1.y), bf16pk(c1.z, c1.w));
                bf16x8 af = *(bf16x8*)&pk2;
                float rmax[4];
                #pragma unroll
                for (int ff = 0; ff < 4; ++ff) {
                    f32x4 z = __builtin_amdgcn_mfma_f32_16x16x32_bf16(
                        af, *(bf16x8*)&Bhi[ff], zf, 0, 0, 0);
                    float m = fmaxf(fmaxf(z[0], z[1]), fmaxf(z[2], z[3]));
                    m = fmaxf(m, __shfl_xor(m, 16));
                    m = fmaxf(m, __shfl_xor(m, 32));
                    rmax[ff] = m;
                }
                float val = (g == 0) ? rmax[0] : (g == 1) ? rmax[1]
                          : (g == 2) ? rmax[2] : rmax[3];
                const int nd = n0l + i;
                float e = fmaxf(val + E[nd * ESTRIDE + g * 16 + c15], 0.f);
                float s = S[nd * ESTRIDE + g * 16 + c15];
                out[(size_t)(nbase + nd) * FOUT + g * 16 + c15] = e + s;
            }

            // node i+1 (buffer B), prefetch node i+3 into B
            float4 d0 = Ba, d1 = Bb;
            if (i + 3 < 8) {
                int nb = IDX[(n0l + i + 3) * IDXS + c15];
                const float* rp2 = x + (size_t)(gbase + nb) * FIN + g * 8;
                Ba = *(const float4*)rp2;
                Bb = *(const float4*)(rp2 + 4);
            }
            {
                int4 pk2 = make_int4(bf16pk(d0.x, d0.y), bf16pk(d0.z, d0.w),
                                     bf16pk(d1.x, d1.y), bf16pk(d1.z, d1.w));
                bf16x8 af = *(bf16x8*)&pk2;
                float rmax[4];
                #pragma unroll
                for (int ff = 0; ff < 4; ++ff) {
                    f32x4 z = __builtin_amdgcn_mfma_f32_16x16x32_bf16(
                        af, *(bf16x8*)&Bhi[ff], zf, 0, 0, 0);
                    float m = fmaxf(fmaxf(z[0], z[1]), fmaxf(z[2], z[3]));
                    m = fmaxf(m, __shfl_xor(m, 16));
                    m = fmaxf(m, __shfl_xor(m, 32));
                    rmax[ff] = m;
                }
                float val = (g == 0) ? rmax[0] : (g == 1) ? rmax[1]
                          : (g == 2) ? rmax[2] : rmax[3];
                const int nd = n0l + i + 1;
                float e = fmaxf(val + E[nd * ESTRIDE + g * 16 + c15], 0.f);
                float s = S[nd * ESTRIDE + g * 16 + c15];
                out[(size_t)(nbase + nd) * FOUT + g * 16 + c15] = e + s;
            }
        }
    }
}

// ---------------------------------------------------------------------------
extern "C" void kernel_launch(void* const* d_in, const int* in_sizes, int n_in,
                              void* d_out, int out_size, void* d_ws, size_t ws_size,
                              hipStream_t stream) {
    const float* x      = (const float*)d_in[0];
    const float* pos    = (const float*)d_in[1];
    const float* W_edge = (const float*)d_in[2];
    const float* b_edge = (const float*)d_in[3];
    const float* W_nn   = (const float*)d_in[4];
    const float* b_nn   = (const float*)d_in[5];

    float4* P4   = (float4*)d_ws;       // 1 MB
    float*  outp = (float*)d_out;

    sq_kernel     <<<NB * NPTS / 256, 256, 0, stream>>>(pos, P4);
    knn_mlp_kernel<<<NB * 32,         512, 0, stream>>>(P4, x, W_edge, b_edge,
                                                        W_nn, b_nn, outp);
}

// Round 15
// 186.415 us; speedup vs baseline: 1.3482x; 1.3482x over previous
//
#include <hip/hip_runtime.h>

// Problem constants (from reference)
#define NB     32      // B
#define NPTS   2048    // N
#define KNN    16      // K
#define FIN    32      // F_IN
#define FOUT   64      // F_OUT

typedef __attribute__((ext_vector_type(8))) short bf16x8;
typedef __attribute__((ext_vector_type(4))) float f32x4;

// RNE float->bf16 pack
__device__ inline unsigned bf16pk(float lo, float hi) {
    unsigned a = __float_as_uint(lo), b = __float_as_uint(hi);
    a = (a + 0x7fffu + ((a >> 16) & 1u)) >> 16;
    b = (b + 0x7fffu + ((b >> 16) & 1u)) >> 16;
    return (a & 0xffffu) | (b << 16);
}

// ---------------------------------------------------------------------------
// R15: R13 base (R14's manual cur[] staging reverted — it forced SGPR->VGPR
// moves, +50% VALU, 131->196us) + 32-candidates-per-dk-merge select.
//  Invariant: dk = multiset of 16 smallest d2 values -> ANY correct top-16
//  network gives bit-identical dk/tthr; rescan+tie machinery (untouched,
//  R13 verbatim) then reproduces indices exactly.
//  New select per 32 candidates: 4x NET8 (desc-8), 2x BMERGED16 (bitonic
//  merge of [desc8|rev(desc8)] valley -> desc-16), elementwise-min combine
//  (16 smallest of 32, bitonic) + BMERGED16, then ONE dk merge
//  (16 fminf + BMERGE16). ~488 instr/32 vs R13's 600. No manual load
//  staging — candidate loads stay in the compiler's s_load pattern.
// ---------------------------------------------------------------------------

#define CEA(x, y) { float _t = fminf(x, y); y = fmaxf(x, y); x = _t; }
#define CED(x, y) { float _t = fmaxf(x, y); y = fminf(x, y); x = _t; }

// bitonic merge-16, ascending (CEA)
#define BMERGE16(dk) \
    CEA(dk[0],dk[8])  CEA(dk[1],dk[9])  CEA(dk[2],dk[10]) CEA(dk[3],dk[11]) \
    CEA(dk[4],dk[12]) CEA(dk[5],dk[13]) CEA(dk[6],dk[14]) CEA(dk[7],dk[15]) \
    CEA(dk[0],dk[4])  CEA(dk[1],dk[5])  CEA(dk[2],dk[6])  CEA(dk[3],dk[7])  \
    CEA(dk[8],dk[12]) CEA(dk[9],dk[13]) CEA(dk[10],dk[14]) CEA(dk[11],dk[15]) \
    CEA(dk[0],dk[2])  CEA(dk[1],dk[3])  CEA(dk[4],dk[6])  CEA(dk[5],dk[7])  \
    CEA(dk[8],dk[10]) CEA(dk[9],dk[11]) CEA(dk[12],dk[14]) CEA(dk[13],dk[15]) \
    CEA(dk[0],dk[1])  CEA(dk[2],dk[3])  CEA(dk[4],dk[5])  CEA(dk[6],dk[7])  \
    CEA(dk[8],dk[9])  CEA(dk[10],dk[11]) CEA(dk[12],dk[13]) CEA(dk[14],dk[15])

// bitonic merge-16, descending (CED) — same network, max-first
#define BMERGED16(v) \
    CED(v[0],v[8])  CED(v[1],v[9])  CED(v[2],v[10]) CED(v[3],v[11]) \
    CED(v[4],v[12]) CED(v[5],v[13]) CED(v[6],v[14]) CED(v[7],v[15]) \
    CED(v[0],v[4])  CED(v[1],v[5])  CED(v[2],v[6])  CED(v[3],v[7])  \
    CED(v[8],v[12]) CED(v[9],v[13]) CED(v[10],v[14]) CED(v[11],v[15]) \
    CED(v[0],v[2])  CED(v[1],v[3])  CED(v[4],v[6])  CED(v[5],v[7])  \
    CED(v[8],v[10]) CED(v[9],v[11]) CED(v[12],v[14]) CED(v[13],v[15]) \
    CED(v[0],v[1])  CED(v[2],v[3])  CED(v[4],v[5])  CED(v[6],v[7])  \
    CED(v[8],v[9])  CED(v[10],v[11]) CED(v[12],v[13]) CED(v[14],v[15])

// sort-8 descending
#define NET8(a) \
    CED(a[0],a[1]) CED(a[2],a[3]) CED(a[4],a[5]) CED(a[6],a[7]) \
    CED(a[0],a[2]) CED(a[1],a[3]) CED(a[4],a[6]) CED(a[5],a[7]) \
    CED(a[1],a[2]) CED(a[5],a[6]) \
    CED(a[0],a[4]) CED(a[1],a[5]) CED(a[2],a[6]) CED(a[3],a[7]) \
    CED(a[2],a[4]) CED(a[3],a[5]) \
    CED(a[1],a[2]) CED(a[3],a[4]) CED(a[5],a[6])

// ================= K1: (x,y,z,sq) precompute (verbatim) ====================
__global__ __launch_bounds__(256) void sq_kernel(
    const float* __restrict__ pos, float4* __restrict__ P4)
{
    const int i = blockIdx.x * 256 + threadIdx.x;   // 0 .. 65535
    const float px = pos[i*3 + 0];
    const float py = pos[i*3 + 1];
    const float pz = pos[i*3 + 2];
    const float sq = __fadd_rn(__fadd_rn(__fmul_rn(px,px), __fmul_rn(py,py)),
                               __fmul_rn(pz,pz));
    P4[i] = make_float4(px, py, pz, sq);
}

// ==================== K2: fused exact 16-NN + edge MLP =====================
#define CH   8
#define CHL  (NPTS / CH)    // 256

// shifted distance: d2' = c.w - 2*dot  (per-query order == true d2 order)
#define D2P(C, DST)                                                        \
    {                                                                      \
        float _dot = __fmaf_rn(me.z, (C).z,                                \
                      __fmaf_rn(me.y, (C).y, __fmul_rn(me.x, (C).x)));     \
        DST = __fmaf_rn(-2.0f, _dot, (C).w);                               \
    }

// 8 candidates starting at JJ -> descending-sorted arr[8]
#define LOAD8(arr, JJ, EXCLF)                                              \
    _Pragma("unroll")                                                      \
    for (int i = 0; i < 8; ++i) {                                          \
        const int j = (JJ) + i;                                            \
        const float4 c = pb4[j];                                           \
        float d2;                                                          \
        D2P(c, d2)                                                         \
        arr[i] = (EXCLF && j == q) ? 1e30f : d2;                           \
    }                                                                      \
    NET8(arr)

// 32 candidates, ONE dk merge (multiset-of-16-smallest invariant)
#define SBATCH32(JB, EXCLF)                                                \
    {                                                                      \
        float b0[8], b1[8], b2[8], b3[8];                                  \
        LOAD8(b0, (JB),      EXCLF)                                        \
        LOAD8(b1, (JB) + 8,  EXCLF)                                        \
        LOAD8(b2, (JB) + 16, EXCLF)                                        \
        LOAD8(b3, (JB) + 24, EXCLF)                                        \
        float v[16], u[16];                                                \
        _Pragma("unroll")                                                  \
        for (int i = 0; i < 8; ++i) { v[i] = b0[i]; v[8+i] = b1[7-i]; }    \
        BMERGED16(v)           /* desc-16 of first 16 */                   \
        _Pragma("unroll")                                                  \
        for (int i = 0; i < 8; ++i) { u[i] = b2[i]; u[8+i] = b3[7-i]; }    \
        BMERGED16(u)           /* desc-16 of second 16 */                  \
        _Pragma("unroll")                                                  \
        for (int i = 0; i < 16; ++i) v[i] = fminf(v[i], u[15-i]);          \
        BMERGED16(v)           /* 16 smallest of the 32, desc */           \
        _Pragma("unroll")                                                  \
        for (int s = 0; s < KNN; ++s) dk[s] = fminf(dk[s], v[s]);          \
        BMERGE16(dk)                                                       \
    }

// rescan append (order within chunk = ascending j -> reference tie-break)
#define APP(DD, JJ)                                                        \
    if ((DD) <= tthr) {                                                    \
        if ((DD) < tthr) {                                                 \
            if (cntS + cntT >= KNN) --cntT;                                \
            JL[base + cntS * 64 + l] = (JJ);                               \
            ++cntS;                                                        \
        } else if (cntS + cntT < KNN) {                                    \
            JL[base + (KNN - 1 - cntT) * 64 + l] = (JJ);                   \
            ++cntT;                                                        \
        }                                                                  \
    }

// batched rescan (R13 verbatim): 16 loads+D2P hoisted, APPs in order
#define RESCB16(JB, EXCLF)                                                 \
    {                                                                      \
        float dd[16];                                                      \
        _Pragma("unroll")                                                  \
        for (int i = 0; i < 16; ++i) {                                     \
            const float4 c = pb4[(JB) + i];                                \
            float d2;                                                      \
            D2P(c, d2)                                                     \
            dd[i] = (EXCLF && ((JB) + i) == q) ? 1e30f : d2;               \
        }                                                                  \
        _Pragma("unroll")                                                  \
        for (int i = 0; i < 16; ++i) { APP(dd[i], (JB) + i) }              \
    }

#define ESTRIDE 66   // padded row stride for E/S
#define IDXS    17   // padded neighbor-list stride (kills gather conflicts)

__global__ __launch_bounds__(512, 8) void knn_mlp_kernel(
    const float4* __restrict__ P4, const float* __restrict__ x,
    const float* __restrict__ W_edge, const float* __restrict__ b_edge,
    const float* __restrict__ W_nn,   const float* __restrict__ b_nn,
    float* __restrict__ out)
{
    // arena: phase A: [V/JL 32768][CNTS 2048][IDX 4352]
    //        phase B: [E 16896][S 16896][... ][IDX 4352]
    __shared__ __attribute__((aligned(16))) char smem[39168];
    float* V    = (float*)smem;
    int*   CNTS = (int*)(smem + 32768);
    int*   IDX  = (int*)(smem + 34816);

    // XCD-aware swizzle: batch b's 32 blocks all share orig%8 == b>>2,
    // i.e. one XCD (dispatch round-robins blockIdx across the 8 XCDs).
    const int orig = blockIdx.x;
    const int b    = ((orig & 7) << 2) | ((orig >> 3) & 3);  // batch 0..31
    const int slab = orig >> 5;                              // slab  0..31
    const int t    = threadIdx.x;
    const int w    = __builtin_amdgcn_readfirstlane(t >> 6);  // chunk id
    const int l    = t & 63;

    const float4* __restrict__ pb4 = P4 + (size_t)b * NPTS;
    const int    q  = slab * 64 + l;     // query within batch (0..2047)
    const float4 me = pb4[q];            // me.w unused (shift dropped)

    // ======================= Phase A: exact 16-NN ==========================
    {
        float dk[KNN];
        #pragma unroll
        for (int s = 0; s < KNN; ++s) dk[s] = 1e30f;

        const int j0  = w * CHL;
        const int exw = slab >> 2;                 // chunk containing q's
        const int lo  = j0 + (slab & 3) * 64;      // 64-range containing q's

        if (w == exw) {
            for (int jb = j0;      jb < lo;        jb += 32) SBATCH32(jb, false)
            for (int jb = lo;      jb < lo + 64;   jb += 32) SBATCH32(jb, true)
            for (int jb = lo + 64; jb < j0 + CHL;  jb += 32) SBATCH32(jb, false)
        } else {
            for (int jb = j0;      jb < j0 + CHL;  jb += 32) SBATCH32(jb, false)
        }

        // cross-chunk merge of the 8 per-chunk top-16 lists
        #pragma unroll
        for (int s = 0; s < KNN; ++s)
            V[(w * KNN + s) * 64 + l] = dk[s];
        __syncthreads();

        for (int c2 = 0; c2 < CH; ++c2) {
            if (c2 == w) continue;
            float v[KNN];
            #pragma unroll
            for (int s2 = 0; s2 < KNN; ++s2)
                v[s2] = V[(c2 * KNN + s2) * 64 + l];
            #pragma unroll
            for (int s = 0; s < KNN; ++s) dk[s] = fminf(dk[s], v[KNN-1-s]);
            BMERGE16(dk)
        }
        const float tthr = dk[KNN-1];
        __syncthreads();            // V dead -> reuse as JL

        // index-recovery rescan from GLOBAL P4 (identical d2' chain),
        // batched 16-wide: loads hoisted, append order preserved
        int* JL = (int*)V;
        const int base = w * KNN * 64;
        int cntS = 0, cntT = 0;
        if (w == exw) {
            for (int j = j0;      j < lo;        j += 16) RESCB16(j, false)
            for (int j = lo;      j < lo + 64;   j += 16) RESCB16(j, true)
            for (int j = lo + 64; j < j0 + CHL;  j += 16) RESCB16(j, false)
        } else {
            for (int j = j0;      j < j0 + CHL;  j += 16) RESCB16(j, false)
        }
        CNTS[w * 64 + l] = cntS | (cntT << 16);
        __syncthreads();

        // gather: wave 0, lane l owns query l (strict first, then ties, in
        // (chunk, index) order == global index order -> reference tie-break)
        if (w == 0) {
            int outc = 0;
            for (int c2 = 0; c2 < CH; ++c2) {
                int cs = CNTS[c2 * 64 + l] & 0xffff;
                for (int s2 = 0; s2 < cs && outc < KNN; ++s2)
                    IDX[l * IDXS + outc++] = JL[(c2 * KNN + s2) * 64 + l];
            }
            for (int c2 = 0; c2 < CH && outc < KNN; ++c2) {
                int ct = CNTS[c2 * 64 + l] >> 16;
                for (int s2 = 0; s2 < ct && outc < KNN; ++s2)
                    IDX[l * IDXS + outc++] =
                        JL[(c2 * KNN + (KNN - 1 - s2)) * 64 + l];
            }
        }
        __syncthreads();            // IDX visible; JL/CNTS dead below
    }

    // ======================= Phase B: MFMA edge MLP ========================
    const int c15 = l & 15;
    const int g   = l >> 4;
    const int nbase = b * NPTS + slab * 64;   // block's first node (global)
    const int gbase = b * NPTS;               // batch start row

    float* E = (float*)smem;            // [64][ESTRIDE]
    float* S = (float*)(smem + 16896);  // [64][ESTRIDE]

    const f32x4 zf = {0.f, 0.f, 0.f, 0.f};

    // ---- B1: base/skip for all 64 nodes -> LDS (wave = 16-node grp x 2 f)
    {
        const int ng = w & 3;            // node group 0..3
        const int f0 = (w >> 2) * 2;     // f-slice base: 0 or 2

        const float* rp = x + (size_t)(nbase + ng * 16 + c15) * FIN + g * 8;
        float4 v0 = *(const float4*)rp;
        float4 v1 = *(const float4*)(rp + 4);
        int4 pk = make_int4(bf16pk(v0.x, v0.y), bf16pk(v0.z, v0.w),
                            bf16pk(v1.x, v1.y), bf16pk(v1.z, v1.w));
        bf16x8 afi = *(bf16x8*)&pk;

        #pragma unroll
        for (int ff = 0; ff < 2; ++ff) {
            const int col = 16 * (f0 + ff) + c15;
            unsigned pd[4], pn[4];
            #pragma unroll
            for (int d = 0; d < 4; ++d) {
                const int k0 = g * 8 + 2 * d;
                float h0 = W_edge[(FIN + k0)     * FOUT + col];
                float h1 = W_edge[(FIN + k0 + 1) * FOUT + col];
                pd[d] = bf16pk(W_edge[k0       * FOUT + col] - h0,
                               W_edge[(k0 + 1) * FOUT + col] - h1);
                pn[d] = bf16pk(W_nn[k0 * FOUT + col], W_nn[(k0+1) * FOUT + col]);
            }
            int4 bd = make_int4(pd[0], pd[1], pd[2], pd[3]);
            int4 bn = make_int4(pn[0], pn[1], pn[2], pn[3]);
            f32x4 baseF = __builtin_amdgcn_mfma_f32_16x16x32_bf16(
                afi, *(bf16x8*)&bd, zf, 0, 0, 0);
            f32x4 skipF = __builtin_amdgcn_mfma_f32_16x16x32_bf16(
                afi, *(bf16x8*)&bn, zf, 0, 0, 0);
            const float be  = b_edge[col];
            const float bnn = b_nn[col];
            #pragma unroll
            for (int reg = 0; reg < 4; ++reg) {
                const int nd = ng * 16 + g * 4 + reg;   // node within block
                E[nd * ESTRIDE + col] = baseF[reg] + be;
                S[nd * ESTRIDE + col] = fmaxf(skipF[reg] + bnn, 0.f);
            }
        }
    }
    __syncthreads();   // E/S visible

    // ---- B2: wave = 8 nodes x ALL 4 f-slices, depth-2 gather prefetch ----
    {
        const int n0l = w * 8;           // first local node of this wave

        int4 Bhi[4];
        #pragma unroll
        for (int ff = 0; ff < 4; ++ff) {
            const int col = 16 * ff + c15;
            unsigned ph[4];
            #pragma unroll
            for (int d = 0; d < 4; ++d) {
                const int k0 = g * 8 + 2 * d;
                ph[d] = bf16pk(W_edge[(FIN + k0)     * FOUT + col],
                               W_edge[(FIN + k0 + 1) * FOUT + col]);
            }
            Bhi[ff] = make_int4(ph[0], ph[1], ph[2], ph[3]);
        }

        // prime depth-2 pipeline (nodes 0 and 1)
        int nbA = IDX[(n0l + 0) * IDXS + c15];
        int nbB = IDX[(n0l + 1) * IDXS + c15];
        const float* rpA = x + (size_t)(gbase + nbA) * FIN + g * 8;
        const float* rpB = x + (size_t)(gbase + nbB) * FIN + g * 8;
        float4 Aa = *(const float4*)rpA, Ab = *(const float4*)(rpA + 4);
        float4 Ba = *(const float4*)rpB, Bb = *(const float4*)(rpB + 4);

        #pragma unroll 1
        for (int i = 0; i < 8; i += 2) {
            // node i (buffer A), prefetch node i+2 into A
            float4 c0 = Aa, c1 = Ab;
            if (i + 2 < 8) {
                int nb = IDX[(n0l + i + 2) * IDXS + c15];
                const float* rp2 = x + (size_t)(gbase + nb) * FIN + g * 8;
                Aa = *(const float4*)rp2;
                Ab = *(const float4*)(rp2 + 4);
            }
            {
                int4 pk2 = make_int4(bf16pk(c0.x, c0.y), bf16pk(c0.z, c0.w),
                                     bf16pk(c1.x, c1.y), bf16pk(c1.z, c1.w));
                bf16x8 af = *(bf16x8*)&pk2;
                float rmax[4];
                #pragma unroll
                for (int ff = 0; ff < 4; ++ff) {
                    f32x4 z = __builtin_amdgcn_mfma_f32_16x16x32_bf16(
                        af, *(bf16x8*)&Bhi[ff], zf, 0, 0, 0);
                    float m = fmaxf(fmaxf(z[0], z[1]), fmaxf(z[2], z[3]));
                    m = fmaxf(m, __shfl_xor(m, 16));
                    m = fmaxf(m, __shfl_xor(m, 32));
                    rmax[ff] = m;
                }
                float val = (g == 0) ? rmax[0] : (g == 1) ? rmax[1]
                          : (g == 2) ? rmax[2] : rmax[3];
                const int nd = n0l + i;
                float e = fmaxf(val + E[nd * ESTRIDE + g * 16 + c15], 0.f);
                float s = S[nd * ESTRIDE + g * 16 + c15];
                out[(size_t)(nbase + nd) * FOUT + g * 16 + c15] = e + s;
            }

            // node i+1 (buffer B), prefetch node i+3 into B
            float4 d0 = Ba, d1 = Bb;
            if (i + 3 < 8) {
                int nb = IDX[(n0l + i + 3) * IDXS + c15];
                const float* rp2 = x + (size_t)(gbase + nb) * FIN + g * 8;
                Ba = *(const float4*)rp2;
                Bb = *(const float4*)(rp2 + 4);
            }
            {
                int4 pk2 = make_int4(bf16pk(d0.x, d0.y), bf16pk(d0.z, d0.w),
                                     bf16pk(d1.x, d1.y), bf16pk(d1.z, d1.w));
                bf16x8 af = *(bf16x8*)&pk2;
                float rmax[4];
                #pragma unroll
                for (int ff = 0; ff < 4; ++ff) {
                    f32x4 z = __builtin_amdgcn_mfma_f32_16x16x32_bf16(
                        af, *(bf16x8*)&Bhi[ff], zf, 0, 0, 0);
                    float m = fmaxf(fmaxf(z[0], z[1]), fmaxf(z[2], z[3]));
                    m = fmaxf(m, __shfl_xor(m, 16));
                    m = fmaxf(m, __shfl_xor(m, 32));
                    rmax[ff] = m;
                }
                float val = (g == 0) ? rmax[0] : (g == 1) ? rmax[1]
                          : (g == 2) ? rmax[2] : rmax[3];
                const int nd = n0l + i + 1;
                float e = fmaxf(val + E[nd * ESTRIDE + g * 16 + c15], 0.f);
                float s = S[nd * ESTRIDE + g * 16 + c15];
                out[(size_t)(nbase + nd) * FOUT + g * 16 + c15] = e + s;
            }
        }
    }
}

// ---------------------------------------------------------------------------
extern "C" void kernel_launch(void* const* d_in, const int* in_sizes, int n_in,
                              void* d_out, int out_size, void* d_ws, size_t ws_size,
                              hipStream_t stream) {
    const float* x      = (const float*)d_in[0];
    const float* pos    = (const float*)d_in[1];
    const float* W_edge = (const float*)d_in[2];
    const float* b_edge = (const float*)d_in[3];
    const float* W_nn   = (const float*)d_in[4];
    const float* b_nn   = (const float*)d_in[5];

    float4* P4   = (float4*)d_ws;       // 1 MB
    float*  outp = (float*)d_out;

    sq_kernel     <<<NB * NPTS / 256, 256, 0, stream>>>(pos, P4);
    knn_mlp_kernel<<<NB * 32,         512, 0, stream>>>(P4, x, W_edge, b_edge,
                                                        W_nn, b_nn, outp);
}

// Round 16
// 184.999 us; speedup vs baseline: 1.3585x; 1.0077x over previous
//
#include <hip/hip_runtime.h>

// Problem constants (from reference)
#define NB     32      // B
#define NPTS   2048    // N
#define KNN    16      // K
#define FIN    32      // F_IN
#define FOUT   64      // F_OUT

typedef __attribute__((ext_vector_type(8))) short bf16x8;
typedef __attribute__((ext_vector_type(4))) float f32x4;

// RNE float->bf16 pack
__device__ inline unsigned bf16pk(float lo, float hi) {
    unsigned a = __float_as_uint(lo), b = __float_as_uint(hi);
    a = (a + 0x7fffu + ((a >> 16) & 1u)) >> 16;
    b = (b + 0x7fffu + ((b >> 16) & 1u)) >> 16;
    return (a & 0xffffu) | (b << 16);
}

// ---------------------------------------------------------------------------
// R16: R15 + R14's parallel gather, ISOLATED.
//  R14 bundled the parallel gather with the bad cur[] staging (regression
//  fully attributed to SGPR->VGPR v_mov flood, VALUBusy 99%); the gather
//  itself passed correctness there (absmax 0.03125). Here it lands on the
//  verified R15 base: all 8 waves place their own chunk's JL entries via
//  CNTS prefix sums (disjoint positions; strict-then-ties order identical
//  to the serial w==0 gather; pos<16 guard == the serial outc<16 cap).
//  Removes the ~2-3k-cycle window where 7 of 8 waves idle at the barrier.
//  Everything else (SBATCH32 select, RESCB16 rescan, XCD swizzle, phase B)
//  is R15 verbatim.
// ---------------------------------------------------------------------------

#define CEA(x, y) { float _t = fminf(x, y); y = fmaxf(x, y); x = _t; }
#define CED(x, y) { float _t = fmaxf(x, y); y = fminf(x, y); x = _t; }

// bitonic merge-16, ascending (CEA)
#define BMERGE16(dk) \
    CEA(dk[0],dk[8])  CEA(dk[1],dk[9])  CEA(dk[2],dk[10]) CEA(dk[3],dk[11]) \
    CEA(dk[4],dk[12]) CEA(dk[5],dk[13]) CEA(dk[6],dk[14]) CEA(dk[7],dk[15]) \
    CEA(dk[0],dk[4])  CEA(dk[1],dk[5])  CEA(dk[2],dk[6])  CEA(dk[3],dk[7])  \
    CEA(dk[8],dk[12]) CEA(dk[9],dk[13]) CEA(dk[10],dk[14]) CEA(dk[11],dk[15]) \
    CEA(dk[0],dk[2])  CEA(dk[1],dk[3])  CEA(dk[4],dk[6])  CEA(dk[5],dk[7])  \
    CEA(dk[8],dk[10]) CEA(dk[9],dk[11]) CEA(dk[12],dk[14]) CEA(dk[13],dk[15]) \
    CEA(dk[0],dk[1])  CEA(dk[2],dk[3])  CEA(dk[4],dk[5])  CEA(dk[6],dk[7])  \
    CEA(dk[8],dk[9])  CEA(dk[10],dk[11]) CEA(dk[12],dk[13]) CEA(dk[14],dk[15])

// bitonic merge-16, descending (CED) — same network, max-first
#define BMERGED16(v) \
    CED(v[0],v[8])  CED(v[1],v[9])  CED(v[2],v[10]) CED(v[3],v[11]) \
    CED(v[4],v[12]) CED(v[5],v[13]) CED(v[6],v[14]) CED(v[7],v[15]) \
    CED(v[0],v[4])  CED(v[1],v[5])  CED(v[2],v[6])  CED(v[3],v[7])  \
    CED(v[8],v[12]) CED(v[9],v[13]) CED(v[10],v[14]) CED(v[11],v[15]) \
    CED(v[0],v[2])  CED(v[1],v[3])  CED(v[4],v[6])  CED(v[5],v[7])  \
    CED(v[8],v[10]) CED(v[9],v[11]) CED(v[12],v[14]) CED(v[13],v[15]) \
    CED(v[0],v[1])  CED(v[2],v[3])  CED(v[4],v[5])  CED(v[6],v[7])  \
    CED(v[8],v[9])  CED(v[10],v[11]) CED(v[12],v[13]) CED(v[14],v[15])

// sort-8 descending
#define NET8(a) \
    CED(a[0],a[1]) CED(a[2],a[3]) CED(a[4],a[5]) CED(a[6],a[7]) \
    CED(a[0],a[2]) CED(a[1],a[3]) CED(a[4],a[6]) CED(a[5],a[7]) \
    CED(a[1],a[2]) CED(a[5],a[6]) \
    CED(a[0],a[4]) CED(a[1],a[5]) CED(a[2],a[6]) CED(a[3],a[7]) \
    CED(a[2],a[4]) CED(a[3],a[5]) \
    CED(a[1],a[2]) CED(a[3],a[4]) CED(a[5],a[6])

// ================= K1: (x,y,z,sq) precompute (verbatim) ====================
__global__ __launch_bounds__(256) void sq_kernel(
    const float* __restrict__ pos, float4* __restrict__ P4)
{
    const int i = blockIdx.x * 256 + threadIdx.x;   // 0 .. 65535
    const float px = pos[i*3 + 0];
    const float py = pos[i*3 + 1];
    const float pz = pos[i*3 + 2];
    const float sq = __fadd_rn(__fadd_rn(__fmul_rn(px,px), __fmul_rn(py,py)),
                               __fmul_rn(pz,pz));
    P4[i] = make_float4(px, py, pz, sq);
}

// ==================== K2: fused exact 16-NN + edge MLP =====================
#define CH   8
#define CHL  (NPTS / CH)    // 256

// shifted distance: d2' = c.w - 2*dot  (per-query order == true d2 order)
#define D2P(C, DST)                                                        \
    {                                                                      \
        float _dot = __fmaf_rn(me.z, (C).z,                                \
                      __fmaf_rn(me.y, (C).y, __fmul_rn(me.x, (C).x)));     \
        DST = __fmaf_rn(-2.0f, _dot, (C).w);                               \
    }

// 8 candidates starting at JJ -> descending-sorted arr[8]
#define LOAD8(arr, JJ, EXCLF)                                              \
    _Pragma("unroll")                                                      \
    for (int i = 0; i < 8; ++i) {                                          \
        const int j = (JJ) + i;                                            \
        const float4 c = pb4[j];                                           \
        float d2;                                                          \
        D2P(c, d2)                                                         \
        arr[i] = (EXCLF && j == q) ? 1e30f : d2;                           \
    }                                                                      \
    NET8(arr)

// 32 candidates, ONE dk merge (multiset-of-16-smallest invariant)
#define SBATCH32(JB, EXCLF)                                                \
    {                                                                      \
        float b0[8], b1[8], b2[8], b3[8];                                  \
        LOAD8(b0, (JB),      EXCLF)                                        \
        LOAD8(b1, (JB) + 8,  EXCLF)                                        \
        LOAD8(b2, (JB) + 16, EXCLF)                                        \
        LOAD8(b3, (JB) + 24, EXCLF)                                        \
        float v[16], u[16];                                                \
        _Pragma("unroll")                                                  \
        for (int i = 0; i < 8; ++i) { v[i] = b0[i]; v[8+i] = b1[7-i]; }    \
        BMERGED16(v)           /* desc-16 of first 16 */                   \
        _Pragma("unroll")                                                  \
        for (int i = 0; i < 8; ++i) { u[i] = b2[i]; u[8+i] = b3[7-i]; }    \
        BMERGED16(u)           /* desc-16 of second 16 */                  \
        _Pragma("unroll")                                                  \
        for (int i = 0; i < 16; ++i) v[i] = fminf(v[i], u[15-i]);          \
        BMERGED16(v)           /* 16 smallest of the 32, desc */           \
        _Pragma("unroll")                                                  \
        for (int s = 0; s < KNN; ++s) dk[s] = fminf(dk[s], v[s]);          \
        BMERGE16(dk)                                                       \
    }

// rescan append (order within chunk = ascending j -> reference tie-break)
#define APP(DD, JJ)                                                        \
    if ((DD) <= tthr) {                                                    \
        if ((DD) < tthr) {                                                 \
            if (cntS + cntT >= KNN) --cntT;                                \
            JL[base + cntS * 64 + l] = (JJ);                               \
            ++cntS;                                                        \
        } else if (cntS + cntT < KNN) {                                    \
            JL[base + (KNN - 1 - cntT) * 64 + l] = (JJ);                   \
            ++cntT;                                                        \
        }                                                                  \
    }

// batched rescan (R13 verbatim): 16 loads+D2P hoisted, APPs in order
#define RESCB16(JB, EXCLF)                                                 \
    {                                                                      \
        float dd[16];                                                      \
        _Pragma("unroll")                                                  \
        for (int i = 0; i < 16; ++i) {                                     \
            const float4 c = pb4[(JB) + i];                                \
            float d2;                                                      \
            D2P(c, d2)                                                     \
            dd[i] = (EXCLF && ((JB) + i) == q) ? 1e30f : d2;               \
        }                                                                  \
        _Pragma("unroll")                                                  \
        for (int i = 0; i < 16; ++i) { APP(dd[i], (JB) + i) }              \
    }

#define ESTRIDE 66   // padded row stride for E/S
#define IDXS    17   // padded neighbor-list stride (kills gather conflicts)

__global__ __launch_bounds__(512, 8) void knn_mlp_kernel(
    const float4* __restrict__ P4, const float* __restrict__ x,
    const float* __restrict__ W_edge, const float* __restrict__ b_edge,
    const float* __restrict__ W_nn,   const float* __restrict__ b_nn,
    float* __restrict__ out)
{
    // arena: phase A: [V/JL 32768][CNTS 2048][IDX 4352]
    //        phase B: [E 16896][S 16896][... ][IDX 4352]
    __shared__ __attribute__((aligned(16))) char smem[39168];
    float* V    = (float*)smem;
    int*   CNTS = (int*)(smem + 32768);
    int*   IDX  = (int*)(smem + 34816);

    // XCD-aware swizzle: batch b's 32 blocks all share orig%8 == b>>2,
    // i.e. one XCD (dispatch round-robins blockIdx across the 8 XCDs).
    const int orig = blockIdx.x;
    const int b    = ((orig & 7) << 2) | ((orig >> 3) & 3);  // batch 0..31
    const int slab = orig >> 5;                              // slab  0..31
    const int t    = threadIdx.x;
    const int w    = __builtin_amdgcn_readfirstlane(t >> 6);  // chunk id
    const int l    = t & 63;

    const float4* __restrict__ pb4 = P4 + (size_t)b * NPTS;
    const int    q  = slab * 64 + l;     // query within batch (0..2047)
    const float4 me = pb4[q];            // me.w unused (shift dropped)

    int* JL = (int*)V;                   // alias valid after merge barrier
    const int base = w * KNN * 64;
    int cntS = 0, cntT = 0;              // live into the parallel gather

    // ======================= Phase A: exact 16-NN ==========================
    {
        float dk[KNN];
        #pragma unroll
        for (int s = 0; s < KNN; ++s) dk[s] = 1e30f;

        const int j0  = w * CHL;
        const int exw = slab >> 2;                 // chunk containing q's
        const int lo  = j0 + (slab & 3) * 64;      // 64-range containing q's

        if (w == exw) {
            for (int jb = j0;      jb < lo;        jb += 32) SBATCH32(jb, false)
            for (int jb = lo;      jb < lo + 64;   jb += 32) SBATCH32(jb, true)
            for (int jb = lo + 64; jb < j0 + CHL;  jb += 32) SBATCH32(jb, false)
        } else {
            for (int jb = j0;      jb < j0 + CHL;  jb += 32) SBATCH32(jb, false)
        }

        // cross-chunk merge of the 8 per-chunk top-16 lists
        #pragma unroll
        for (int s = 0; s < KNN; ++s)
            V[(w * KNN + s) * 64 + l] = dk[s];
        __syncthreads();

        for (int c2 = 0; c2 < CH; ++c2) {
            if (c2 == w) continue;
            float v[KNN];
            #pragma unroll
            for (int s2 = 0; s2 < KNN; ++s2)
                v[s2] = V[(c2 * KNN + s2) * 64 + l];
            #pragma unroll
            for (int s = 0; s < KNN; ++s) dk[s] = fminf(dk[s], v[KNN-1-s]);
            BMERGE16(dk)
        }
        const float tthr = dk[KNN-1];
        __syncthreads();            // V dead -> reuse as JL

        // index-recovery rescan from GLOBAL P4 (identical d2' chain),
        // batched 16-wide: loads hoisted, append order preserved
        if (w == exw) {
            for (int j = j0;      j < lo;        j += 16) RESCB16(j, false)
            for (int j = lo;      j < lo + 64;   j += 16) RESCB16(j, true)
            for (int j = lo + 64; j < j0 + CHL;  j += 16) RESCB16(j, false)
        } else {
            for (int j = j0;      j < j0 + CHL;  j += 16) RESCB16(j, false)
        }
        CNTS[w * 64 + l] = cntS | (cntT << 16);
        __syncthreads();
    }

    // ---- parallel gather: all 8 waves, prefix-sum placement ----
    // Wave w places its own chunk's entries. Order identical to the serial
    // gather: strict entries in (chunk, index) order, then ties in (chunk,
    // index) order, capped at 16. Positions disjoint across waves.
    // (Correctness validated on-device in R14, which passed with this code.)
    {
        int pS = 0, pT = 0, totS = 0;
        #pragma unroll
        for (int c2 = 0; c2 < CH; ++c2) {
            int cc = CNTS[c2 * 64 + l];
            int cs = cc & 0xffff, ct = cc >> 16;
            if (c2 < w) { pS += cs; pT += ct; }
            totS += cs;
        }
        for (int s2 = 0; s2 < cntS; ++s2) {
            int pos = pS + s2;                    // provably < 16; guard anyway
            if (pos < KNN) IDX[l * IDXS + pos] = JL[base + s2 * 64 + l];
        }
        for (int s2 = 0; s2 < cntT; ++s2) {
            int pos = totS + pT + s2;
            if (pos < KNN)
                IDX[l * IDXS + pos] = JL[base + (KNN - 1 - s2) * 64 + l];
        }
    }
    __syncthreads();            // IDX visible; JL/CNTS dead below

    // ======================= Phase B: MFMA edge MLP ========================
    const int c15 = l & 15;
    const int g   = l >> 4;
    const int nbase = b * NPTS + slab * 64;   // block's first node (global)
    const int gbase = b * NPTS;               // batch start row

    float* E = (float*)smem;            // [64][ESTRIDE]
    float* S = (float*)(smem + 16896);  // [64][ESTRIDE]

    const f32x4 zf = {0.f, 0.f, 0.f, 0.f};

    // ---- B1: base/skip for all 64 nodes -> LDS (wave = 16-node grp x 2 f)
    {
        const int ng = w & 3;            // node group 0..3
        const int f0 = (w >> 2) * 2;     // f-slice base: 0 or 2

        const float* rp = x + (size_t)(nbase + ng * 16 + c15) * FIN + g * 8;
        float4 v0 = *(const float4*)rp;
        float4 v1 = *(const float4*)(rp + 4);
        int4 pk = make_int4(bf16pk(v0.x, v0.y), bf16pk(v0.z, v0.w),
                            bf16pk(v1.x, v1.y), bf16pk(v1.z, v1.w));
        bf16x8 afi = *(bf16x8*)&pk;

        #pragma unroll
        for (int ff = 0; ff < 2; ++ff) {
            const int col = 16 * (f0 + ff) + c15;
            unsigned pd[4], pn[4];
            #pragma unroll
            for (int d = 0; d < 4; ++d) {
                const int k0 = g * 8 + 2 * d;
                float h0 = W_edge[(FIN + k0)     * FOUT + col];
                float h1 = W_edge[(FIN + k0 + 1) * FOUT + col];
                pd[d] = bf16pk(W_edge[k0       * FOUT + col] - h0,
                               W_edge[(k0 + 1) * FOUT + col] - h1);
                pn[d] = bf16pk(W_nn[k0 * FOUT + col], W_nn[(k0+1) * FOUT + col]);
            }
            int4 bd = make_int4(pd[0], pd[1], pd[2], pd[3]);
            int4 bn = make_int4(pn[0], pn[1], pn[2], pn[3]);
            f32x4 baseF = __builtin_amdgcn_mfma_f32_16x16x32_bf16(
                afi, *(bf16x8*)&bd, zf, 0, 0, 0);
            f32x4 skipF = __builtin_amdgcn_mfma_f32_16x16x32_bf16(
                afi, *(bf16x8*)&bn, zf, 0, 0, 0);
            const float be  = b_edge[col];
            const float bnn = b_nn[col];
            #pragma unroll
            for (int reg = 0; reg < 4; ++reg) {
                const int nd = ng * 16 + g * 4 + reg;   // node within block
                E[nd * ESTRIDE + col] = baseF[reg] + be;
                S[nd * ESTRIDE + col] = fmaxf(skipF[reg] + bnn, 0.f);
            }
        }
    }
    __syncthreads();   // E/S visible

    // ---- B2: wave = 8 nodes x ALL 4 f-slices, depth-2 gather prefetch ----
    {
        const int n0l = w * 8;           // first local node of this wave

        int4 Bhi[4];
        #pragma unroll
        for (int ff = 0; ff < 4; ++ff) {
            const int col = 16 * ff + c15;
            unsigned ph[4];
            #pragma unroll
            for (int d = 0; d < 4; ++d) {
                const int k0 = g * 8 + 2 * d;
                ph[d] = bf16pk(W_edge[(FIN + k0)     * FOUT + col],
                               W_edge[(FIN + k0 + 1) * FOUT + col]);
            }
            Bhi[ff] = make_int4(ph[0], ph[1], ph[2], ph[3]);
        }

        // prime depth-2 pipeline (nodes 0 and 1)
        int nbA = IDX[(n0l + 0) * IDXS + c15];
        int nbB = IDX[(n0l + 1) * IDXS + c15];
        const float* rpA = x + (size_t)(gbase + nbA) * FIN + g * 8;
        const float* rpB = x + (size_t)(gbase + nbB) * FIN + g * 8;
        float4 Aa = *(const float4*)rpA, Ab = *(const float4*)(rpA + 4);
        float4 Ba = *(const float4*)rpB, Bb = *(const float4*)(rpB + 4);

        #pragma unroll 1
        for (int i = 0; i < 8; i += 2) {
            // node i (buffer A), prefetch node i+2 into A
            float4 c0 = Aa, c1 = Ab;
            if (i + 2 < 8) {
                int nb = IDX[(n0l + i + 2) * IDXS + c15];
                const float* rp2 = x + (size_t)(gbase + nb) * FIN + g * 8;
                Aa = *(const float4*)rp2;
                Ab = *(const float4*)(rp2 + 4);
            }
            {
                int4 pk2 = make_int4(bf16pk(c0.x, c0.y), bf16pk(c0.z, c0.w),
                                     bf16pk(c1.x, c1.y), bf16pk(c1.z, c1.w));
                bf16x8 af = *(bf16x8*)&pk2;
                float rmax[4];
                #pragma unroll
                for (int ff = 0; ff < 4; ++ff) {
                    f32x4 z = __builtin_amdgcn_mfma_f32_16x16x32_bf16(
                        af, *(bf16x8*)&Bhi[ff], zf, 0, 0, 0);
                    float m = fmaxf(fmaxf(z[0], z[1]), fmaxf(z[2], z[3]));
                    m = fmaxf(m, __shfl_xor(m, 16));
                    m = fmaxf(m, __shfl_xor(m, 32));
                    rmax[ff] = m;
                }
                float val = (g == 0) ? rmax[0] : (g == 1) ? rmax[1]
                          : (g == 2) ? rmax[2] : rmax[3];
                const int nd = n0l + i;
                float e = fmaxf(val + E[nd * ESTRIDE + g * 16 + c15], 0.f);
                float s = S[nd * ESTRIDE + g * 16 + c15];
                out[(size_t)(nbase + nd) * FOUT + g * 16 + c15] = e + s;
            }

            // node i+1 (buffer B), prefetch node i+3 into B
            float4 d0 = Ba, d1 = Bb;
            if (i + 3 < 8) {
                int nb = IDX[(n0l + i + 3) * IDXS + c15];
                const float* rp2 = x + (size_t)(gbase + nb) * FIN + g * 8;
                Ba = *(const float4*)rp2;
                Bb = *(const float4*)(rp2 + 4);
            }
            {
                int4 pk2 = make_int4(bf16pk(d0.x, d0.y), bf16pk(d0.z, d0.w),
                                     bf16pk(d1.x, d1.y), bf16pk(d1.z, d1.w));
                bf16x8 af = *(bf16x8*)&pk2;
                float rmax[4];
                #pragma unroll
                for (int ff = 0; ff < 4; ++ff) {
                    f32x4 z = __builtin_amdgcn_mfma_f32_16x16x32_bf16(
                        af, *(bf16x8*)&Bhi[ff], zf, 0, 0, 0);
                    float m = fmaxf(fmaxf(z[0], z[1]), fmaxf(z[2], z[3]));
                    m = fmaxf(m, __shfl_xor(m, 16));
                    m = fmaxf(m, __shfl_xor(m, 32));
                    rmax[ff] = m;
                }
                float val = (g == 0) ? rmax[0] : (g == 1) ? rmax[1]
                          : (g == 2) ? rmax[2] : rmax[3];
                const int nd = n0l + i + 1;
                float e = fmaxf(val + E[nd * ESTRIDE + g * 16 + c15], 0.f);
                float s = S[nd * ESTRIDE + g * 16 + c15];
                out[(size_t)(nbase + nd) * FOUT + g * 16 + c15] = e + s;
            }
        }
    }
}

// ---------------------------------------------------------------------------
extern "C" void kernel_launch(void* const* d_in, const int* in_sizes, int n_in,
                              void* d_out, int out_size, void* d_ws, size_t ws_size,
                              hipStream_t stream) {
    const float* x      = (const float*)d_in[0];
    const float* pos    = (const float*)d_in[1];
    const float* W_edge = (const float*)d_in[2];
    const float* b_edge = (const float*)d_in[3];
    const float* W_nn   = (const float*)d_in[4];
    const float* b_nn   = (const float*)d_in[5];

    float4* P4   = (float4*)d_ws;       // 1 MB
    float*  outp = (float*)d_out;

    sq_kernel     <<<NB * NPTS / 256, 256, 0, stream>>>(pos, P4);
    knn_mlp_kernel<<<NB * 32,         512, 0, stream>>>(P4, x, W_edge, b_edge,
                                                        W_nn, b_nn, outp);
}